// Round 3
// baseline (7340.138 us; speedup 1.0000x reference)
//
#include <hip/hip_runtime.h>

#define HIDN 128
#define TILE 64          // samples per block
#define STRIDE 132       // LDS row stride in floats
#define JSTRIDE 17       // jf LDS row stride (floats)

// Sequential-k f32 FMA chain: acc[ii] accumulates k ascending 0..127 with a
// single accumulator per output element. This replicates the BLAS sgemm
// microkernel contraction order (numpy f32 reference) bit-exactly, so the
// ReLU mask sign decisions match the reference. Do NOT fold the bias into
// the accumulator init — numpy adds bias AFTER the matmul.
__device__ __forceinline__ void matvec32_seq(const float* __restrict__ Wg,
                                             const float* __restrict__ vin,
                                             float* __restrict__ acc)
{
    #pragma unroll 4
    for (int jc = 0; jc < 32; ++jc) {
        const float4 av = *(const float4*)(vin + jc * 4);
        #pragma unroll
        for (int ii = 0; ii < 32; ++ii) {
            const float4 w = *(const float4*)(Wg + ii * HIDN + jc * 4);
            float a = acc[ii];
            a = fmaf(w.x, av.x, a);
            a = fmaf(w.y, av.y, a);
            a = fmaf(w.z, av.z, a);
            a = fmaf(w.w, av.w, a);
            acc[ii] = a;
        }
    }
}

__global__ __launch_bounds__(256, 2)
void wnn_jac_kernel(const float* __restrict__ u,
                    const float* __restrict__ W1, const float* __restrict__ b1,
                    const float* __restrict__ W2, const float* __restrict__ b2,
                    const float* __restrict__ W3, const float* __restrict__ b3,
                    const float* __restrict__ W4,
                    float* __restrict__ out, int Btot)
{
    __shared__ __align__(16) float bufA[TILE * STRIDE];
    __shared__ __align__(16) float bufB[TILE * STRIDE];
    __shared__ float jf[TILE * JSTRIDE];

    const int tid = threadIdx.x;
    const int s   = tid & 63;          // sample within tile (= lane)
    const int g   = tid >> 6;          // wave id = hidden-row group
    const int i0  = g * 32;
    const long sg = (long)blockIdx.x * TILE + s;
    const bool valid = (sg < (long)Btot);

    float4 uv = make_float4(0.f, 0.f, 0.f, 0.f);
    if (valid) uv = *(const float4*)(u + sg * 4);

    unsigned m1 = 0, m2 = 0, m3 = 0;

    // ---------- forward layer 1: h = (seq-fma chain from 0) + b ----------
    #pragma unroll
    for (int ii = 0; ii < 32; ++ii) {
        const int i = i0 + ii;
        const float4 w = *(const float4*)(W1 + i * 4);
        float h = 0.f;
        h = fmaf(w.x, uv.x, h);
        h = fmaf(w.y, uv.y, h);
        h = fmaf(w.z, uv.z, h);
        h = fmaf(w.w, uv.w, h);
        h = h + b1[i];
        if (h > 0.f) m1 |= (1u << ii);
        bufA[s * STRIDE + i] = fmaxf(h, 0.f);
    }
    __syncthreads();

    // ---------- forward layer 2 ----------
    {
        float acc[32];
        #pragma unroll
        for (int ii = 0; ii < 32; ++ii) acc[ii] = 0.f;
        matvec32_seq(W2 + (long)i0 * HIDN, bufA + s * STRIDE, acc);
        #pragma unroll
        for (int ii = 0; ii < 32; ++ii) {
            const float h = acc[ii] + b2[i0 + ii];
            if (h > 0.f) m2 |= (1u << ii);
            bufB[s * STRIDE + i0 + ii] = fmaxf(h, 0.f);
        }
    }
    __syncthreads();

    // ---------- forward layer 3 (mask only) ----------
    {
        float acc[32];
        #pragma unroll
        for (int ii = 0; ii < 32; ++ii) acc[ii] = 0.f;
        matvec32_seq(W3 + (long)i0 * HIDN, bufB + s * STRIDE, acc);
        #pragma unroll
        for (int ii = 0; ii < 32; ++ii) {
            const float h = acc[ii] + b3[i0 + ii];
            if (h > 0.f) m3 |= (1u << ii);
        }
    }
    // bufA's last readers were in layer 2 (protected by that sync); bufB's
    // last readers (layer 3) are protected by the sync after the v1 write.

    // ---------- 4 tangent passes (f32) ----------
    for (int k = 0; k < 4; ++k) {
        // v1 = m1 .* W1[:,k] -> bufA
        #pragma unroll
        for (int ii = 0; ii < 32; ++ii) {
            const int i = i0 + ii;
            const float w1ik = W1[i * 4 + k];
            bufA[s * STRIDE + i] = ((m1 >> ii) & 1u) ? w1ik : 0.f;
        }
        __syncthreads();
        // v2 = m2 .* (W2 @ v1) -> bufB
        {
            float acc[32];
            #pragma unroll
            for (int ii = 0; ii < 32; ++ii) acc[ii] = 0.f;
            matvec32_seq(W2 + (long)i0 * HIDN, bufA + s * STRIDE, acc);
            #pragma unroll
            for (int ii = 0; ii < 32; ++ii)
                bufB[s * STRIDE + i0 + ii] = ((m2 >> ii) & 1u) ? acc[ii] : 0.f;
        }
        __syncthreads();
        // v3 = m3 .* (W3 @ v2) -> bufA
        {
            float acc[32];
            #pragma unroll
            for (int ii = 0; ii < 32; ++ii) acc[ii] = 0.f;
            matvec32_seq(W3 + (long)i0 * HIDN, bufB + s * STRIDE, acc);
            #pragma unroll
            for (int ii = 0; ii < 32; ++ii)
                bufA[s * STRIDE + i0 + ii] = ((m3 >> ii) & 1u) ? acc[ii] : 0.f;
        }
        __syncthreads();
        // Jf[g,k] = W4[g,:] . v3
        {
            float jacc = 0.f;
            const float* vrow = bufA + s * STRIDE;
            #pragma unroll 8
            for (int jc = 0; jc < 32; ++jc) {
                const float4 vv = *(const float4*)(vrow + jc * 4);
                const float4 w  = *(const float4*)(W4 + g * HIDN + jc * 4);
                jacc = fmaf(w.x, vv.x, jacc);
                jacc = fmaf(w.y, vv.y, jacc);
                jacc = fmaf(w.z, vv.z, jacc);
                jacc = fmaf(w.w, vv.w, jacc);
            }
            jf[s * JSTRIDE + g * 4 + k] = jacc;
        }
        __syncthreads();
    }

    // ---------- epilogue: out[b][g][c] = Jf[b][c][g] - Jf[b][g][c] ----------
    if (valid) {
        const float* jrow = jf + s * JSTRIDE;
        float4 o;
        o.x = jrow[0 * 4 + g] - jrow[g * 4 + 0];
        o.y = jrow[1 * 4 + g] - jrow[g * 4 + 1];
        o.z = jrow[2 * 4 + g] - jrow[g * 4 + 2];
        o.w = jrow[3 * 4 + g] - jrow[g * 4 + 3];
        *(float4*)(out + sg * 16 + g * 4) = o;
    }
}

extern "C" void kernel_launch(void* const* d_in, const int* in_sizes, int n_in,
                              void* d_out, int out_size, void* d_ws, size_t ws_size,
                              hipStream_t stream)
{
    const float* u  = (const float*)d_in[0];
    const float* W1 = (const float*)d_in[1];
    const float* b1 = (const float*)d_in[2];
    const float* W2 = (const float*)d_in[3];
    const float* b2 = (const float*)d_in[4];
    const float* W3 = (const float*)d_in[5];
    const float* b3 = (const float*)d_in[6];
    const float* W4 = (const float*)d_in[7];
    // d_in[8] = b4: unused (bias does not enter the Jacobian)
    float* out = (float*)d_out;

    const int B = in_sizes[0] / 4;
    const int nblocks = (B + TILE - 1) / TILE;
    hipLaunchKernelGGL(wnn_jac_kernel, dim3(nblocks), dim3(256), 0, stream,
                       u, W1, b1, W2, b2, W3, b3, W4, out, B);
}

// Round 4
// 2346.222 us; speedup vs baseline: 3.1285x; 3.1285x over previous
//
#include <hip/hip_runtime.h>

#define HIDN 128
#define TILE 64          // samples per block
#define STRIDE 132       // LDS row stride in floats (33×16B, odd quad count -> balanced banks; measured 0 conflicts)
#define JSTRIDE 17       // jf LDS row stride (floats)

// 16-row sequential-k f32 matvec: acc[ii] += W[r0+ii, :] . vin[:], k ascending.
// Single accumulator per output, k strictly ascending 0..127 -> bit-identical
// to the numpy/BLAS f32 contraction (mask-critical). acc[16] + unroll 2 keeps
// the live set ~80 VGPRs: NO spills (R3's acc[32]/unroll-4 version spilled ->
// 27.8 GB of scratch traffic per dispatch).
__device__ __forceinline__ void matvec16_seq(const float* __restrict__ Wg,   // W + r0*HIDN
                                             const float* __restrict__ vin,  // LDS row, 16B aligned
                                             float* __restrict__ acc)
{
    #pragma unroll 2
    for (int jc = 0; jc < 32; ++jc) {
        const float4 av = *(const float4*)(vin + jc * 4);
        #pragma unroll
        for (int ii = 0; ii < 16; ++ii) {
            const float4 w = *(const float4*)(Wg + ii * HIDN + jc * 4);
            float a = acc[ii];
            a = fmaf(w.x, av.x, a);
            a = fmaf(w.y, av.y, a);
            a = fmaf(w.z, av.z, a);
            a = fmaf(w.w, av.w, a);
            acc[ii] = a;
        }
    }
}

__global__ __launch_bounds__(256, 2)
void wnn_jac_kernel(const float* __restrict__ u,
                    const float* __restrict__ W1, const float* __restrict__ b1,
                    const float* __restrict__ W2, const float* __restrict__ b2,
                    const float* __restrict__ W3, const float* __restrict__ b3,
                    const float* __restrict__ W4,
                    float* __restrict__ out, int Btot)
{
    __shared__ __align__(16) float bufA[TILE * STRIDE];
    __shared__ __align__(16) float bufB[TILE * STRIDE];
    __shared__ float jf[TILE * JSTRIDE];

    const int tid = threadIdx.x;
    const int s   = tid & 63;          // sample within tile (= lane)
    const int g   = tid >> 6;          // wave id = hidden-row group
    const int i0  = g * 32;
    const long sg = (long)blockIdx.x * TILE + s;
    const bool valid = (sg < (long)Btot);

    float4 uv = make_float4(0.f, 0.f, 0.f, 0.f);
    if (valid) uv = *(const float4*)(u + sg * 4);

    unsigned m1 = 0, m2 = 0, m3 = 0;

    // ---------- forward layer 1: h = (seq-fma chain from 0) + b ----------
    #pragma unroll
    for (int ii = 0; ii < 32; ++ii) {
        const int i = i0 + ii;
        const float4 w = *(const float4*)(W1 + i * 4);
        float h = 0.f;
        h = fmaf(w.x, uv.x, h);
        h = fmaf(w.y, uv.y, h);
        h = fmaf(w.z, uv.z, h);
        h = fmaf(w.w, uv.w, h);
        h = h + b1[i];
        if (h > 0.f) m1 |= (1u << ii);
        bufA[s * STRIDE + i] = fmaxf(h, 0.f);
    }
    __syncthreads();

    // ---------- forward layer 2 (two 16-row passes) ----------
    #pragma unroll
    for (int half = 0; half < 2; ++half) {
        const int r0 = i0 + half * 16;
        float acc[16];
        #pragma unroll
        for (int ii = 0; ii < 16; ++ii) acc[ii] = 0.f;
        matvec16_seq(W2 + (long)r0 * HIDN, bufA + s * STRIDE, acc);
        #pragma unroll
        for (int ii = 0; ii < 16; ++ii) {
            const float h = acc[ii] + b2[r0 + ii];
            if (h > 0.f) m2 |= (1u << (half * 16 + ii));
            bufB[s * STRIDE + r0 + ii] = fmaxf(h, 0.f);
        }
    }
    __syncthreads();

    // ---------- forward layer 3 (mask only, two 16-row passes) ----------
    #pragma unroll
    for (int half = 0; half < 2; ++half) {
        const int r0 = i0 + half * 16;
        float acc[16];
        #pragma unroll
        for (int ii = 0; ii < 16; ++ii) acc[ii] = 0.f;
        matvec16_seq(W3 + (long)r0 * HIDN, bufB + s * STRIDE, acc);
        #pragma unroll
        for (int ii = 0; ii < 16; ++ii) {
            const float h = acc[ii] + b3[r0 + ii];
            if (h > 0.f) m3 |= (1u << (half * 16 + ii));
        }
    }
    // bufA's last readers were layer 2 (protected by the sync after layer 2);
    // bufB's last readers (layer 3) are protected by the sync after the v1 write.

    // ---------- 4 tangent passes (f32) ----------
    for (int k = 0; k < 4; ++k) {
        // v1 = m1 .* W1[:,k] -> bufA
        #pragma unroll
        for (int ii = 0; ii < 32; ++ii) {
            const int i = i0 + ii;
            const float w1ik = W1[i * 4 + k];
            bufA[s * STRIDE + i] = ((m1 >> ii) & 1u) ? w1ik : 0.f;
        }
        __syncthreads();
        // v2 = m2 .* (W2 @ v1) -> bufB
        #pragma unroll
        for (int half = 0; half < 2; ++half) {
            const int r0 = i0 + half * 16;
            float acc[16];
            #pragma unroll
            for (int ii = 0; ii < 16; ++ii) acc[ii] = 0.f;
            matvec16_seq(W2 + (long)r0 * HIDN, bufA + s * STRIDE, acc);
            #pragma unroll
            for (int ii = 0; ii < 16; ++ii)
                bufB[s * STRIDE + r0 + ii] = ((m2 >> (half * 16 + ii)) & 1u) ? acc[ii] : 0.f;
        }
        __syncthreads();
        // v3 = m3 .* (W3 @ v2) -> bufA
        #pragma unroll
        for (int half = 0; half < 2; ++half) {
            const int r0 = i0 + half * 16;
            float acc[16];
            #pragma unroll
            for (int ii = 0; ii < 16; ++ii) acc[ii] = 0.f;
            matvec16_seq(W3 + (long)r0 * HIDN, bufB + s * STRIDE, acc);
            #pragma unroll
            for (int ii = 0; ii < 16; ++ii)
                bufA[s * STRIDE + r0 + ii] = ((m3 >> (half * 16 + ii)) & 1u) ? acc[ii] : 0.f;
        }
        __syncthreads();
        // Jf[g,k] = W4[g,:] . v3
        {
            float jacc = 0.f;
            const float* vrow = bufA + s * STRIDE;
            #pragma unroll 8
            for (int jc = 0; jc < 32; ++jc) {
                const float4 vv = *(const float4*)(vrow + jc * 4);
                const float4 w  = *(const float4*)(W4 + g * HIDN + jc * 4);
                jacc = fmaf(w.x, vv.x, jacc);
                jacc = fmaf(w.y, vv.y, jacc);
                jacc = fmaf(w.z, vv.z, jacc);
                jacc = fmaf(w.w, vv.w, jacc);
            }
            jf[s * JSTRIDE + g * 4 + k] = jacc;
        }
        __syncthreads();
    }

    // ---------- epilogue: out[b][g][c] = Jf[b][c][g] - Jf[b][g][c] ----------
    if (valid) {
        const float* jrow = jf + s * JSTRIDE;
        float4 o;
        o.x = jrow[0 * 4 + g] - jrow[g * 4 + 0];
        o.y = jrow[1 * 4 + g] - jrow[g * 4 + 1];
        o.z = jrow[2 * 4 + g] - jrow[g * 4 + 2];
        o.w = jrow[3 * 4 + g] - jrow[g * 4 + 3];
        *(float4*)(out + sg * 16 + g * 4) = o;
    }
}

extern "C" void kernel_launch(void* const* d_in, const int* in_sizes, int n_in,
                              void* d_out, int out_size, void* d_ws, size_t ws_size,
                              hipStream_t stream)
{
    const float* u  = (const float*)d_in[0];
    const float* W1 = (const float*)d_in[1];
    const float* b1 = (const float*)d_in[2];
    const float* W2 = (const float*)d_in[3];
    const float* b2 = (const float*)d_in[4];
    const float* W3 = (const float*)d_in[5];
    const float* b3 = (const float*)d_in[6];
    const float* W4 = (const float*)d_in[7];
    // d_in[8] = b4: unused (bias does not enter the Jacobian)
    float* out = (float*)d_out;

    const int B = in_sizes[0] / 4;
    const int nblocks = (B + TILE - 1) / TILE;
    hipLaunchKernelGGL(wnn_jac_kernel, dim3(nblocks), dim3(256), 0, stream,
                       u, W1, b1, W2, b2, W3, b3, W4, out, B);
}